// Round 7
// baseline (1996.918 us; speedup 1.0000x reference)
//
#include <hip/hip_runtime.h>

typedef unsigned short u16;
typedef unsigned int u32;
typedef unsigned long long u64;
typedef short s16x8 __attribute__((ext_vector_type(8)));
typedef float f32x4 __attribute__((ext_vector_type(4)));
typedef __bf16 bf16x2 __attribute__((ext_vector_type(2)));

#define BTH 2097152  // 16*512*256

__device__ __forceinline__ u16 f2bf(float f) {
  u32 u = __float_as_uint(f);
  u32 r = (u + 0x7FFFu + ((u >> 16) & 1u)) >> 16;  // RNE
  return (u16)r;
}
__device__ __forceinline__ float bf2f(u16 u) {
  return __uint_as_float(((u32)u) << 16);
}
__device__ __forceinline__ float sigm_(float x) { return 1.f / (1.f + __expf(-x)); }
__device__ __forceinline__ float tanh_(float x) {
  x = fminf(15.f, fmaxf(-15.f, x));
  float e = __expf(2.f * x);
  return (e - 1.f) / (e + 1.f);
}

#if defined(__has_builtin)
#if __has_builtin(__builtin_amdgcn_fdot2_f32_bf16)
#define HAVE_BF16_DOT2 1
#endif
#endif

__device__ __forceinline__ float dotp(u32 a, u32 b, float acc) {
#ifdef HAVE_BF16_DOT2
  return __builtin_amdgcn_fdot2_f32_bf16(__builtin_bit_cast(bf16x2, a),
                                         __builtin_bit_cast(bf16x2, b), acc, false);
#else
  acc += bf2f((u16)(a & 0xFFFFu)) * bf2f((u16)(b & 0xFFFFu));
  acc += bf2f((u16)(a >> 16)) * bf2f((u16)(b >> 16));
  return acc;
#endif
}

__device__ __forceinline__ void async_cp16(const u16* g, u16* l) {
  __builtin_amdgcn_global_load_lds(
      (const __attribute__((address_space(1))) void*)g,
      (__attribute__((address_space(3))) void*)l, 16, 0, 0);
}

// one mLSTM step for one batch: consumes h row (16 u32 from LDS), Yc, wx;
// updates c, hn. All lanes of the 8-lane cluster produce identical hn.
__device__ __forceinline__ void lstm_step(
    const uint4 (&Ur)[4][4], const uint4 (&Yc)[4], const u32* hrow,
    float w0, float w1, float w2, float w3, float bbias,
    float& c, float& hn) {
  uint4 hq[4];
  {
    const uint4* lp = (const uint4*)hrow;
    hq[0] = lp[0]; hq[1] = lp[1]; hq[2] = lp[2]; hq[3] = lp[3];
  }
  float a0 = 0.f, a1 = 0.f, a2 = 0.f, a3 = 0.f, am = 0.f;
#pragma unroll
  for (int j = 0; j < 4; ++j) {
    u32 h0 = hq[j].x, h1 = hq[j].y, h2 = hq[j].z, h3 = hq[j].w;
    a0 = dotp(Ur[0][j].x, h0, a0); a0 = dotp(Ur[0][j].y, h1, a0);
    a0 = dotp(Ur[0][j].z, h2, a0); a0 = dotp(Ur[0][j].w, h3, a0);
    a1 = dotp(Ur[1][j].x, h0, a1); a1 = dotp(Ur[1][j].y, h1, a1);
    a1 = dotp(Ur[1][j].z, h2, a1); a1 = dotp(Ur[1][j].w, h3, a1);
    a2 = dotp(Ur[2][j].x, h0, a2); a2 = dotp(Ur[2][j].y, h1, a2);
    a2 = dotp(Ur[2][j].z, h2, a2); a2 = dotp(Ur[2][j].w, h3, a2);
    a3 = dotp(Ur[3][j].x, h0, a3); a3 = dotp(Ur[3][j].y, h1, a3);
    a3 = dotp(Ur[3][j].z, h2, a3); a3 = dotp(Ur[3][j].w, h3, a3);
    am = dotp(Yc[j].x, h0, am);   am = dotp(Yc[j].y, h1, am);
    am = dotp(Yc[j].z, h2, am);   am = dotp(Yc[j].w, h3, am);
  }
#pragma unroll
  for (int mk = 1; mk < 8; mk <<= 1) {
    a0 += __shfl_xor(a0, mk, 8);
    a1 += __shfl_xor(a1, mk, 8);
    a2 += __shfl_xor(a2, mk, 8);
    a3 += __shfl_xor(a3, mk, 8);
    am += __shfl_xor(am, mk, 8);
  }
  float gi = sigm_(a0 + w0);
  float gf = sigm_(a1 + w1);
  float go = sigm_(a2 + w2);
  float gg = tanh_(a3 + w3);
  float mm = tanh_(am + bbias);
  c = gf * c + gi * gg + 0.1f * mm;
  hn = go * tanh_(c);
}

// ---------------- prep: all casts + B transpose + state zero, ONE launch ----
__global__ __launch_bounds__(256) void prep_kernel(
    const float* __restrict__ x, const float* __restrict__ Ww,
    const float* __restrict__ Uw, const float* __restrict__ Bw,
    u16* __restrict__ xb, u16* __restrict__ Wbt, u16* __restrict__ Ubt,
    u16* __restrict__ Btt, u64* __restrict__ stz) {
  const int bid = blockIdx.x;
  const int tid = threadIdx.x;
  if (bid < 8192) {
    int e = bid * 256 + tid;
    int d = e & 255;
    int r = e >> 8;
    int bb = r >> 9, t = r & 511;
    xb[(size_t)((t << 4) | bb) * 256 + d] = f2bf(x[e]);
  } else if (bid < 9216) {
    int e = (bid - 8192) * 256 + tid;
    Wbt[e] = f2bf(Ww[e]);
  } else if (bid < 10240) {
    int e = (bid - 9216) * 256 + tid;
    Ubt[e] = f2bf(Uw[e]);
  } else if (bid < 14336) {
    __shared__ float T[64][65];
    int tb = bid - 10240;
    int o = tb >> 4, xi = tb & 15;
    const int d0 = (xi >> 2) * 64;
    const int h0 = (xi & 3) * 64;
    const float* src = Bw + (size_t)o * 65536;
#pragma unroll
    for (int k = 0; k < 16; ++k) {
      int idx = tid + k * 256;
      int rr = idx >> 6, cc = idx & 63;
      T[rr][cc] = src[(size_t)(d0 + rr) * 256 + h0 + cc];
    }
    __syncthreads();
#pragma unroll
    for (int k = 0; k < 16; ++k) {
      int idx = tid + k * 256;
      int rr = idx >> 6, cc = idx & 63;
      Btt[(size_t)(o * 256 + h0 + rr) * 256 + d0 + cc] = f2bf(T[cc][rr]);
    }
  } else {
    for (int i = tid; i < 6144; i += 256) stz[i] = 0ull;
  }
}

// Fused pipeline kernel: blocks [0,sblocks) run the scan (2-way batch
// interleave, see below); [sblocks, sblocks+wxblocks) wx-GEMM; the rest
// Y-GEMM for the NEXT chunk into Ygm. GEMM Y stores are NONTEMPORAL: Y is
// written once, read next-dispatch from other XCDs -> streaming to HBM
// avoids the end-of-dispatch dirty-L2 writeback drain.
__global__ __launch_bounds__(512, 2) void fused_kernel(
    const u16* __restrict__ Ysc, const float* __restrict__ wx,
    const u16* __restrict__ Ubt, const float* __restrict__ Bb,
    float* cbuf, u64* hdata, float* __restrict__ out, int t0, int Tcur,
    const u16* __restrict__ Ag, const u16* __restrict__ Bg,
    u16* __restrict__ Ygm,
    const u16* __restrict__ Wbt, const float* __restrict__ Wb,
    const float* __restrict__ Ub, float* __restrict__ wxout,
    int sblocks, int wxblocks) {
  __shared__ __align__(16) char smem[24576];
  const int tid = threadIdx.x;
  if ((int)blockIdx.x >= sblocks) {
    // ---------------- GEMM path (wx or Y), 128x256 tile ------------------
    u16* As = (u16*)smem;           // 128 x 32
    u16* Bs = (u16*)(smem + 8192);  // 256 x 32
    const int gi = (int)blockIdx.x - sblocks;
    const bool iswx = gi < wxblocks;
    int mt, n0;
    const u16* Bop;
    if (iswx) {
      mt = gi >> 2;            // 64 m-tiles over 8192 rows
      n0 = (gi & 3) * 256;     // N=1024
      Bop = Wbt;
    } else {
      int g2 = gi - wxblocks;
      mt = g2 >> 8;            // m-tiles over the chunk
      n0 = (g2 & 255) * 256;   // N=65536
      Bop = Bg;
    }
    const u16* A = Ag + (size_t)mt * 128 * 256;
    const int wave = tid >> 6, lane = tid & 63;
    const int wm = (wave >> 2) * 64, wn = (wave & 3) * 64;
    const int qm = lane & 15, quad = lane >> 4;
    f32x4 acc[4][4] = {};
    const size_t ga = (size_t)(tid >> 2) * 256 + (tid & 3) * 8;
    const int c0 = tid, c1 = tid + 512;
    const size_t gb0 = (size_t)(n0 + (c0 >> 2)) * 256 + (c0 & 3) * 8;
    const size_t gb1 = (size_t)(n0 + (c1 >> 2)) * 256 + (c1 & 3) * 8;
    for (int k0 = 0; k0 < 256; k0 += 32) {
      __syncthreads();
      async_cp16(A + ga + k0, As + tid * 8);
      async_cp16(Bop + gb0 + k0, Bs + c0 * 8);
      async_cp16(Bop + gb1 + k0, Bs + c1 * 8);
      __syncthreads();
      s16x8 af[4], bfr[4];
#pragma unroll
      for (int i = 0; i < 4; ++i)
        af[i] = *(const s16x8*)&As[(wm + i * 16 + qm) * 32 + quad * 8];
#pragma unroll
      for (int j = 0; j < 4; ++j)
        bfr[j] = *(const s16x8*)&Bs[(wn + j * 16 + qm) * 32 + quad * 8];
#pragma unroll
      for (int i = 0; i < 4; ++i)
#pragma unroll
        for (int j = 0; j < 4; ++j)
          acc[i][j] = __builtin_amdgcn_mfma_f32_16x16x32_bf16(af[i], bfr[j], acc[i][j], 0, 0, 0);
    }
    if (iswx) {
#pragma unroll
      for (int i = 0; i < 4; ++i) {
        int rg = mt * 128 + wm + i * 16 + quad * 4;
#pragma unroll
        for (int j = 0; j < 4; ++j) {
          int cg = n0 + wn + j * 16 + qm;
          float bias = Wb[cg] + Ub[cg];
#pragma unroll
          for (int r = 0; r < 4; ++r)
            wxout[(size_t)(rg + r) * 1024 + cg] = acc[i][j][r] + bias;
        }
      }
    } else {
#pragma unroll
      for (int i = 0; i < 4; ++i) {
        int rg = wm + i * 16 + quad * 4;
#pragma unroll
        for (int j = 0; j < 4; ++j) {
          int cg = n0 + wn + j * 16 + qm;
#pragma unroll
          for (int r = 0; r < 4; ++r)
            __builtin_nontemporal_store(
                f2bf(acc[i][j][r]),
                &Ygm[(size_t)(mt * 128 + rg + r) * 65536 + cg]);
        }
      }
    }
    return;
  }
  // ---------------- scan path: 2-way batch-interleaved -------------------
  // 32 blocks: p = bid&3 (o-slice), bh = bid>>2 in [0,8): batches bh, bh+8.
  // Per batch the protocol is byte-identical to r2 (4-block rendezvous via
  // self-validating u64 words, parity dbuf, wave-0-style cooperative poll).
  // Wave0 polls A, wave1 polls B concurrently; computing B(t) hides the
  // store->LLC->detect latency of A(t+1) and vice versa: per-step cost
  // drops from C+L to ~(C+L)/2. Max-lead safety unchanged: h(t+2) words
  // can only exist after every wave finished step t+1, which implies all
  // step-t LDS reads completed, so lh[ab][par] reuse at t+2 is safe.
  u32(*lh)[2][128] = (u32(*)[2][128])smem;   // [ab][par][128]
  int* lflag = (int*)(smem + 4096);          // [ab*2+par]
  const int bh = blockIdx.x >> 2;            // batch A = bh, B = bh+8
  const int p = blockIdx.x & 3;
  const int oo = tid >> 3;  // 0..63
  const int s = tid & 7;    // K octant: k in [32s, 32s+32)
  const int o = (p << 6) + oo;
  const int wave = tid >> 6;
  const int lane = tid & 63;

  uint4 Ur[4][4];
  const uint4* Ub4 = (const uint4*)Ubt;
#pragma unroll
  for (int g = 0; g < 4; ++g) {
    int row = (g << 8) + o;
#pragma unroll
    for (int j = 0; j < 4; ++j) Ur[g][j] = Ub4[(size_t)row * 32 + s * 4 + j];
  }

  const float bbias = Bb[o];
  float cA = cbuf[(bh << 8) + o];
  float cB = cbuf[((bh + 8) << 8) + o];
  if (tid < 4) lflag[tid] = t0 - 1;

  const int tend = t0 + Tcur;
  const u16* YpA = Ysc + (size_t)bh * 65536 + (size_t)o * 256 + s * 32;
  const u16* YpB = YpA + (size_t)8 * 65536;
  uint4 YcA[4], YcB[4];
  {
    const uint4* ya = (const uint4*)YpA;
    YcA[0] = ya[0]; YcA[1] = ya[1]; YcA[2] = ya[2]; YcA[3] = ya[3];
    const uint4* yb = (const uint4*)YpB;
    YcB[0] = yb[0]; YcB[1] = yb[1]; YcB[2] = yb[2]; YcB[3] = yb[3];
  }
  const float* wxpA0 = wx + ((size_t)t0 * 16 + bh) * 1024 + o;
  float wA0 = wxpA0[0], wA1 = wxpA0[256], wA2 = wxpA0[512], wA3 = wxpA0[768];
  const float* wxpB0 = wxpA0 + 8 * 1024;
  float wB0 = wxpB0[0], wB1 = wxpB0[256], wB2 = wxpB0[512], wB3 = wxpB0[768];
  float hnA = 0.f, hnB = 0.f;
  u64* hgA = hdata + ((size_t)bh << 8);
  u64* hgB = hdata + ((size_t)(bh + 8) << 8);
  __syncthreads();  // lflag init visible

  for (int t = t0; t < tend; ++t) {
    const int par = t & 1;
    // concurrent cooperative polls: wave0 -> batch A, wave1 -> batch B
    if (wave == 0) {
      const u64* hp = hgA + (par << 7) + (lane << 1);
      u64 v0, v1;
      for (;;) {
        v0 = __hip_atomic_load(hp, __ATOMIC_RELAXED, __HIP_MEMORY_SCOPE_AGENT);
        v1 = __hip_atomic_load(hp + 1, __ATOMIC_RELAXED, __HIP_MEMORY_SCOPE_AGENT);
        int ok = ((u32)(v0 >> 32) == (u32)t) & ((u32)(v1 >> 32) == (u32)t);
        if (__all(ok)) break;
      }
      lh[0][par][(lane << 1)] = (u32)v0;
      lh[0][par][(lane << 1) + 1] = (u32)v1;
      __hip_atomic_store(&lflag[par], t, __ATOMIC_RELEASE, __HIP_MEMORY_SCOPE_WORKGROUP);
    } else if (wave == 1) {
      const u64* hp = hgB + (par << 7) + (lane << 1);
      u64 v0, v1;
      for (;;) {
        v0 = __hip_atomic_load(hp, __ATOMIC_RELAXED, __HIP_MEMORY_SCOPE_AGENT);
        v1 = __hip_atomic_load(hp + 1, __ATOMIC_RELAXED, __HIP_MEMORY_SCOPE_AGENT);
        int ok = ((u32)(v0 >> 32) == (u32)t) & ((u32)(v1 >> 32) == (u32)t);
        if (__all(ok)) break;
      }
      lh[1][par][(lane << 1)] = (u32)v0;
      lh[1][par][(lane << 1) + 1] = (u32)v1;
      __hip_atomic_store(&lflag[2 + par], t, __ATOMIC_RELEASE, __HIP_MEMORY_SCOPE_WORKGROUP);
    }
    int dn = (t + 1 < tend) ? (t + 1 - t0) : (t - t0);
    int tn = (t + 1 < tend) ? (t + 1) : t;

    // ----- batch A -----
    while (__hip_atomic_load(&lflag[par], __ATOMIC_ACQUIRE, __HIP_MEMORY_SCOPE_WORKGROUP) < t) {}
    lstm_step(Ur, YcA, &lh[0][par][s << 4], wA0, wA1, wA2, wA3, bbias, cA, hnA);
    {
      float hnext = __shfl_down(hnA, 8);
      if (s == 0) {
        if (!(oo & 1)) {
          u32 pk = (u32)f2bf(hnA) | ((u32)f2bf(hnext) << 16);
          u64 pk64 = ((u64)(u32)(t + 1) << 32) | (u64)pk;
          __hip_atomic_store(hgA + (((size_t)((t + 1) & 1)) << 7) + (p << 5) + (oo >> 1),
                             pk64, __ATOMIC_RELAXED, __HIP_MEMORY_SCOPE_AGENT);
        }
        out[((size_t)bh * 512 + t) * 256 + o] = hnA;
      }
    }
    // prefetch A(t+1) -- latency hides under B's poll-wait + compute
    {
      const uint4* ynp = (const uint4*)(YpA + (size_t)dn * 1048576);
      YcA[0] = ynp[0]; YcA[1] = ynp[1]; YcA[2] = ynp[2]; YcA[3] = ynp[3];
      const float* nwp = wx + ((size_t)tn * 16 + bh) * 1024 + o;
      wA0 = nwp[0]; wA1 = nwp[256]; wA2 = nwp[512]; wA3 = nwp[768];
    }

    // ----- batch B -----
    while (__hip_atomic_load(&lflag[2 + par], __ATOMIC_ACQUIRE, __HIP_MEMORY_SCOPE_WORKGROUP) < t) {}
    lstm_step(Ur, YcB, &lh[1][par][s << 4], wB0, wB1, wB2, wB3, bbias, cB, hnB);
    {
      float hnext = __shfl_down(hnB, 8);
      if (s == 0) {
        if (!(oo & 1)) {
          u32 pk = (u32)f2bf(hnB) | ((u32)f2bf(hnext) << 16);
          u64 pk64 = ((u64)(u32)(t + 1) << 32) | (u64)pk;
          __hip_atomic_store(hgB + (((size_t)((t + 1) & 1)) << 7) + (p << 5) + (oo >> 1),
                             pk64, __ATOMIC_RELAXED, __HIP_MEMORY_SCOPE_AGENT);
        }
        out[((size_t)(bh + 8) * 512 + t) * 256 + o] = hnB;
      }
    }
    // prefetch B(t+1) -- hides under next iteration's A poll-wait
    {
      const uint4* ynp = (const uint4*)(YpB + (size_t)dn * 1048576);
      YcB[0] = ynp[0]; YcB[1] = ynp[1]; YcB[2] = ynp[2]; YcB[3] = ynp[3];
      const float* nwp = wx + ((size_t)tn * 16 + bh + 8) * 1024 + o;
      wB0 = nwp[0]; wB1 = nwp[256]; wB2 = nwp[512]; wB3 = nwp[768];
    }
  }
  if (s == 0) {
    cbuf[(bh << 8) + o] = cA;
    cbuf[((bh + 8) << 8) + o] = cB;
    out[(size_t)BTH + (bh << 8) + o] = hnA;
    out[(size_t)BTH + 4096 + (bh << 8) + o] = cA;
    out[(size_t)BTH + ((bh + 8) << 8) + o] = hnB;
    out[(size_t)BTH + 4096 + ((bh + 8) << 8) + o] = cB;
  }
}

extern "C" void kernel_launch(void* const* d_in, const int* in_sizes, int n_in,
                              void* d_out, int out_size, void* d_ws, size_t ws_size,
                              hipStream_t stream) {
  const float* x  = (const float*)d_in[0];
  const float* Ww = (const float*)d_in[1];
  const float* Wb = (const float*)d_in[2];
  const float* Uw = (const float*)d_in[3];
  const float* Ub = (const float*)d_in[4];
  const float* Bw = (const float*)d_in[5];
  const float* Bb = (const float*)d_in[6];
  float* out = (float*)d_out;

  char* ws = (char*)d_ws;
  const size_t WX_B  = (size_t)512 * 16 * 1024 * 4;  // 33.5 MB
  const size_t XB_B  = (size_t)8192 * 256 * 2;       // 4.2 MB
  const size_t BTT_B = (size_t)65536 * 256 * 2;      // 33.5 MB
  const size_t WBT_B = (size_t)1024 * 256 * 2;       // 0.5 MB
  const size_t UBT_B = (size_t)1024 * 256 * 2;       // 0.5 MB
  const size_t CB_B  = 16384;                        // cbuf 16*256 f32
  const size_t HD_B  = 32768;                        // hdata 16*2*128 u64
  const size_t ST_B  = CB_B + HD_B;                  // 49152 = 6144 u64
  const size_t fixedB = WX_B + XB_B + BTT_B + WBT_B + UBT_B + ST_B;
  size_t avail = (ws_size > fixedB) ? (ws_size - fixedB) : 0;
  long Tc = (long)(avail / (2 * 2097152));  // two Y buffers (double-buffer)
  if (Tc > 64) Tc = 64;
  Tc &= ~7L;
  if (Tc < 8) Tc = 8;

  size_t YB   = (size_t)Tc * 2097152;
  u16* Y0     = (u16*)ws;
  u16* Y1     = (u16*)(ws + YB);
  float* wx   = (float*)(ws + 2 * YB);
  u16* xb     = (u16*)(ws + 2 * YB + WX_B);
  u16* Btt    = (u16*)(ws + 2 * YB + WX_B + XB_B);
  u16* Wbt    = (u16*)(ws + 2 * YB + WX_B + XB_B + BTT_B);
  u16* Ubt    = (u16*)(ws + 2 * YB + WX_B + XB_B + BTT_B + WBT_B);
  char* st    = ws + 2 * YB + WX_B + XB_B + BTT_B + WBT_B + UBT_B;
  float* cbuf = (float*)st;
  u64* hdata  = (u64*)(st + CB_B);

  prep_kernel<<<14337, 256, 0, stream>>>(x, Ww, Uw, Bw, xb, Wbt, Ubt, Btt, (u64*)st);

  // fused0: wx-GEMM (256 blocks) + Y-GEMM for chunk 0 (no scan)
  {
    int Tc0 = (int)Tc;
    int ng0 = (Tc0 * 16 / 128) * 256;
    fused_kernel<<<256 + ng0, 512, 0, stream>>>(
        nullptr, wx, Ubt, Bb, cbuf, hdata, out, 0, 0,
        xb, Btt, Y0, Wbt, Wb, Ub, wx, 0, 256);
  }
  int cidx = 0;
  for (int t0 = 0; t0 < 512; t0 += (int)Tc, ++cidx) {
    int Tcur = (512 - t0 < (int)Tc) ? (512 - t0) : (int)Tc;
    int t0n = t0 + Tcur;
    u16* Ysc = (cidx & 1) ? Y1 : Y0;
    u16* Ygm = (cidx & 1) ? Y0 : Y1;
    int ng = 0;
    const u16* Ag = xb;
    if (t0n < 512) {
      int Tcn = (512 - t0n < (int)Tc) ? (512 - t0n) : (int)Tc;
      ng = (Tcn * 16 / 128) * 256;
      Ag = xb + (size_t)t0n * 4096;
    }
    fused_kernel<<<32 + ng, 512, 0, stream>>>(
        Ysc, wx, Ubt, Bb, cbuf, hdata, out, t0, Tcur,
        Ag, Btt, Ygm, Wbt, Wb, Ub, wx, 32, 0);
  }
}

// Round 8
// 1356.038 us; speedup vs baseline: 1.4726x; 1.4726x over previous
//
#include <hip/hip_runtime.h>

typedef unsigned short u16;
typedef unsigned int u32;
typedef unsigned long long u64;
typedef short s16x8 __attribute__((ext_vector_type(8)));
typedef float f32x4 __attribute__((ext_vector_type(4)));
typedef __bf16 bf16x2 __attribute__((ext_vector_type(2)));

#define BTH 2097152  // 16*512*256

__device__ __forceinline__ u16 f2bf(float f) {
  u32 u = __float_as_uint(f);
  u32 r = (u + 0x7FFFu + ((u >> 16) & 1u)) >> 16;  // RNE
  return (u16)r;
}
__device__ __forceinline__ float bf2f(u16 u) {
  return __uint_as_float(((u32)u) << 16);
}
__device__ __forceinline__ float sigm_(float x) { return 1.f / (1.f + __expf(-x)); }
__device__ __forceinline__ float tanh_(float x) {
  x = fminf(15.f, fmaxf(-15.f, x));
  float e = __expf(2.f * x);
  return (e - 1.f) / (e + 1.f);
}

#if defined(__has_builtin)
#if __has_builtin(__builtin_amdgcn_fdot2_f32_bf16)
#define HAVE_BF16_DOT2 1
#endif
#endif

__device__ __forceinline__ float dotp(u32 a, u32 b, float acc) {
#ifdef HAVE_BF16_DOT2
  return __builtin_amdgcn_fdot2_f32_bf16(__builtin_bit_cast(bf16x2, a),
                                         __builtin_bit_cast(bf16x2, b), acc, false);
#else
  acc += bf2f((u16)(a & 0xFFFFu)) * bf2f((u16)(b & 0xFFFFu));
  acc += bf2f((u16)(a >> 16)) * bf2f((u16)(b >> 16));
  return acc;
#endif
}

__device__ __forceinline__ void async_cp16(const u16* g, u16* l) {
  __builtin_amdgcn_global_load_lds(
      (const __attribute__((address_space(1))) void*)g,
      (__attribute__((address_space(3))) void*)l, 16, 0, 0);
}

// ---------------- prep: all casts + B transpose + state zero, ONE launch ----
__global__ __launch_bounds__(256) void prep_kernel(
    const float* __restrict__ x, const float* __restrict__ Ww,
    const float* __restrict__ Uw, const float* __restrict__ Bw,
    u16* __restrict__ xb, u16* __restrict__ Wbt, u16* __restrict__ Ubt,
    u16* __restrict__ Btt, u64* __restrict__ stz) {
  const int bid = blockIdx.x;
  const int tid = threadIdx.x;
  if (bid < 8192) {
    int e = bid * 256 + tid;
    int d = e & 255;
    int r = e >> 8;
    int bb = r >> 9, t = r & 511;
    xb[(size_t)((t << 4) | bb) * 256 + d] = f2bf(x[e]);
  } else if (bid < 9216) {
    int e = (bid - 8192) * 256 + tid;
    Wbt[e] = f2bf(Ww[e]);
  } else if (bid < 10240) {
    int e = (bid - 9216) * 256 + tid;
    Ubt[e] = f2bf(Uw[e]);
  } else if (bid < 14336) {
    __shared__ float T[64][65];
    int tb = bid - 10240;
    int o = tb >> 4, xi = tb & 15;
    const int d0 = (xi >> 2) * 64;
    const int h0 = (xi & 3) * 64;
    const float* src = Bw + (size_t)o * 65536;
#pragma unroll
    for (int k = 0; k < 16; ++k) {
      int idx = tid + k * 256;
      int rr = idx >> 6, cc = idx & 63;
      T[rr][cc] = src[(size_t)(d0 + rr) * 256 + h0 + cc];
    }
    __syncthreads();
#pragma unroll
    for (int k = 0; k < 16; ++k) {
      int idx = tid + k * 256;
      int rr = idx >> 6, cc = idx & 63;
      Btt[(size_t)(o * 256 + h0 + rr) * 256 + d0 + cc] = f2bf(T[cc][rr]);
    }
  } else {
    for (int i = tid; i < 6144; i += 256) stz[i] = 0ull;
  }
}

// Fused pipeline kernel (r6 structure, proven): blocks [0,sblocks) run the
// scan for chunk (t0,Tcur) reading Ysc; blocks [sblocks, sblocks+wxblocks)
// run the wx-GEMM (N=1024, f32+bias out); remaining blocks run the Y-GEMM
// for the NEXT chunk into Ygm (128x256 tile, 512 threads, 8 waves 2x4).
// Chunk GEMM->scan dependency is enforced by launch boundaries (stream
// serialization); within a launch, scan c and gemm c+1 touch disjoint Y
// buffers. GEMM blocks never wait on anything -> no deadlock possible.
// LDS union: scan 1.5 KB, gemm 24 KB. Plain (cached) Y stores: L2/LLC
// absorbs them and the next dispatch's scan reads hit LLC (r7 showed
// nontemporal doubles HBM traffic and regresses).
__global__ __launch_bounds__(512, 2) void fused_kernel(
    const u16* __restrict__ Ysc, const float* __restrict__ wx,
    const u16* __restrict__ Ubt, const float* __restrict__ Bb,
    float* cbuf, u64* hdata, float* __restrict__ out, int t0, int Tcur,
    const u16* __restrict__ Ag, const u16* __restrict__ Bg,
    u16* __restrict__ Ygm,
    const u16* __restrict__ Wbt, const float* __restrict__ Wb,
    const float* __restrict__ Ub, float* __restrict__ wxout,
    int sblocks, int wxblocks) {
  __shared__ __align__(16) char smem[24576];
  const int tid = threadIdx.x;
  if ((int)blockIdx.x >= sblocks) {
    // ---------------- GEMM path (wx or Y), 128x256 tile ------------------
    u16* As = (u16*)smem;           // 128 x 32
    u16* Bs = (u16*)(smem + 8192);  // 256 x 32
    const int gi = (int)blockIdx.x - sblocks;
    const bool iswx = gi < wxblocks;
    int mt, n0;
    const u16* Bop;
    if (iswx) {
      mt = gi >> 2;            // 64 m-tiles over 8192 rows
      n0 = (gi & 3) * 256;     // N=1024
      Bop = Wbt;
    } else {
      int g2 = gi - wxblocks;
      mt = g2 >> 8;            // m-tiles over the chunk
      n0 = (g2 & 255) * 256;   // N=65536
      Bop = Bg;
    }
    const u16* A = Ag + (size_t)mt * 128 * 256;
    const int wave = tid >> 6, lane = tid & 63;
    const int wm = (wave >> 2) * 64, wn = (wave & 3) * 64;
    const int qm = lane & 15, quad = lane >> 4;
    f32x4 acc[4][4] = {};
    const size_t ga = (size_t)(tid >> 2) * 256 + (tid & 3) * 8;
    const int c0 = tid, c1 = tid + 512;
    const size_t gb0 = (size_t)(n0 + (c0 >> 2)) * 256 + (c0 & 3) * 8;
    const size_t gb1 = (size_t)(n0 + (c1 >> 2)) * 256 + (c1 & 3) * 8;
    for (int k0 = 0; k0 < 256; k0 += 32) {
      __syncthreads();
      async_cp16(A + ga + k0, As + tid * 8);
      async_cp16(Bop + gb0 + k0, Bs + c0 * 8);
      async_cp16(Bop + gb1 + k0, Bs + c1 * 8);
      __syncthreads();
      s16x8 af[4], bfr[4];
#pragma unroll
      for (int i = 0; i < 4; ++i)
        af[i] = *(const s16x8*)&As[(wm + i * 16 + qm) * 32 + quad * 8];
#pragma unroll
      for (int j = 0; j < 4; ++j)
        bfr[j] = *(const s16x8*)&Bs[(wn + j * 16 + qm) * 32 + quad * 8];
#pragma unroll
      for (int i = 0; i < 4; ++i)
#pragma unroll
        for (int j = 0; j < 4; ++j)
          acc[i][j] = __builtin_amdgcn_mfma_f32_16x16x32_bf16(af[i], bfr[j], acc[i][j], 0, 0, 0);
    }
    if (iswx) {
#pragma unroll
      for (int i = 0; i < 4; ++i) {
        int rg = mt * 128 + wm + i * 16 + quad * 4;
#pragma unroll
        for (int j = 0; j < 4; ++j) {
          int cg = n0 + wn + j * 16 + qm;
          float bias = Wb[cg] + Ub[cg];
#pragma unroll
          for (int r = 0; r < 4; ++r)
            wxout[(size_t)(rg + r) * 1024 + cg] = acc[i][j][r] + bias;
        }
      }
    } else {
#pragma unroll
      for (int i = 0; i < 4; ++i) {
        int rg = wm + i * 16 + quad * 4;  // row within chunk (Ygm pre-offset)
#pragma unroll
        for (int j = 0; j < 4; ++j) {
          int cg = n0 + wn + j * 16 + qm;
#pragma unroll
          for (int r = 0; r < 4; ++r)
            Ygm[(size_t)(mt * 128 + rg + r) * 65536 + cg] = f2bf(acc[i][j][r]);
        }
      }
    }
    return;
  }
  // ---------------- scan path (byte-identical protocol to r2/r3/r6) ------
  u32(*lh)[128] = (u32(*)[128])smem;
  int* lflag = (int*)(smem + 1024);
  const int b = blockIdx.x >> 2;
  const int p = blockIdx.x & 3;
  const int oo = tid >> 3;  // 0..63
  const int s = tid & 7;    // K octant: k in [32s, 32s+32)
  const int o = (p << 6) + oo;
  const int wave = tid >> 6;
  const int lane = tid & 63;

  uint4 Ur[4][4];
  const uint4* Ub4 = (const uint4*)Ubt;
#pragma unroll
  for (int g = 0; g < 4; ++g) {
    int row = (g << 8) + o;
#pragma unroll
    for (int j = 0; j < 4; ++j) Ur[g][j] = Ub4[(size_t)row * 32 + s * 4 + j];
  }

  float c = cbuf[(b << 8) + o];
  const float bbias = Bb[o];
  if (tid < 2) lflag[tid] = t0 - 1;

  const int tend = t0 + Tcur;
  const u16* Yp = Ysc + (size_t)b * 65536 + (size_t)o * 256 + s * 32;
  uint4 Yc[4];
  {
    const uint4* y0 = (const uint4*)Yp;
    Yc[0] = y0[0]; Yc[1] = y0[1]; Yc[2] = y0[2]; Yc[3] = y0[3];
  }
  const float* wxp0 = wx + ((size_t)t0 * 16 + b) * 1024 + o;
  float w0 = wxp0[0], w1 = wxp0[256], w2 = wxp0[512], w3 = wxp0[768];
  float hn = 0.f;
  u64* hg = hdata + ((size_t)b << 8);  // [par][128] u64 words per batch
  __syncthreads();  // lflag init visible

  for (int t = t0; t < tend; ++t) {
    // prefetch next step's x-dependent data (fills during the h wait)
    int dn = (t + 1 < tend) ? (t + 1 - t0) : (t - t0);
    const uint4* ynp = (const uint4*)(Yp + (size_t)dn * 1048576);
    uint4 yn0 = ynp[0], yn1 = ynp[1], yn2 = ynp[2], yn3 = ynp[3];
    int tn = (t + 1 < tend) ? (t + 1) : t;
    const float* nwp = wx + ((size_t)tn * 16 + b) * 1024 + o;
    float nw0 = nwp[0], nw1 = nwp[256], nw2 = nwp[512], nw3 = nwp[768];

    const int par = t & 1;
    if (wave == 0) {
      const u64* hp = hg + (par << 7) + (lane << 1);
      u64 v0, v1;
      for (;;) {
        v0 = __hip_atomic_load(hp, __ATOMIC_RELAXED, __HIP_MEMORY_SCOPE_AGENT);
        v1 = __hip_atomic_load(hp + 1, __ATOMIC_RELAXED, __HIP_MEMORY_SCOPE_AGENT);
        int ok = ((u32)(v0 >> 32) == (u32)t) & ((u32)(v1 >> 32) == (u32)t);
        if (__all(ok)) break;
      }
      lh[par][(lane << 1)] = (u32)v0;
      lh[par][(lane << 1) + 1] = (u32)v1;
      __hip_atomic_store(&lflag[par], t, __ATOMIC_RELEASE, __HIP_MEMORY_SCOPE_WORKGROUP);
    } else {
      while (__hip_atomic_load(&lflag[par], __ATOMIC_ACQUIRE, __HIP_MEMORY_SCOPE_WORKGROUP) < t) {}
    }

    uint4 hq[4];
    {
      const uint4* lp = (const uint4*)&lh[par][s << 4];
      hq[0] = lp[0]; hq[1] = lp[1]; hq[2] = lp[2]; hq[3] = lp[3];
    }

    float a0 = 0.f, a1 = 0.f, a2 = 0.f, a3 = 0.f, am = 0.f;
#pragma unroll
    for (int j = 0; j < 4; ++j) {
      u32 h0 = hq[j].x, h1 = hq[j].y, h2 = hq[j].z, h3 = hq[j].w;
      a0 = dotp(Ur[0][j].x, h0, a0); a0 = dotp(Ur[0][j].y, h1, a0);
      a0 = dotp(Ur[0][j].z, h2, a0); a0 = dotp(Ur[0][j].w, h3, a0);
      a1 = dotp(Ur[1][j].x, h0, a1); a1 = dotp(Ur[1][j].y, h1, a1);
      a1 = dotp(Ur[1][j].z, h2, a1); a1 = dotp(Ur[1][j].w, h3, a1);
      a2 = dotp(Ur[2][j].x, h0, a2); a2 = dotp(Ur[2][j].y, h1, a2);
      a2 = dotp(Ur[2][j].z, h2, a2); a2 = dotp(Ur[2][j].w, h3, a2);
      a3 = dotp(Ur[3][j].x, h0, a3); a3 = dotp(Ur[3][j].y, h1, a3);
      a3 = dotp(Ur[3][j].z, h2, a3); a3 = dotp(Ur[3][j].w, h3, a3);
      am = dotp(Yc[j].x, h0, am);   am = dotp(Yc[j].y, h1, am);
      am = dotp(Yc[j].z, h2, am);   am = dotp(Yc[j].w, h3, am);
    }
#pragma unroll
    for (int mk = 1; mk < 8; mk <<= 1) {
      a0 += __shfl_xor(a0, mk, 8);
      a1 += __shfl_xor(a1, mk, 8);
      a2 += __shfl_xor(a2, mk, 8);
      a3 += __shfl_xor(a3, mk, 8);
      am += __shfl_xor(am, mk, 8);
    }
    float gi = sigm_(a0 + w0);
    float gf = sigm_(a1 + w1);
    float go = sigm_(a2 + w2);
    float gg = tanh_(a3 + w3);
    float mm = tanh_(am + bbias);
    c = gf * c + gi * gg + 0.1f * mm;
    hn = go * tanh_(c);  // identical across the 8-lane cluster

    float hnext = __shfl_down(hn, 8);  // oo+1 cluster's hn (same wave)
    if (s == 0) {
      if (!(oo & 1)) {
        u32 pk = (u32)f2bf(hn) | ((u32)f2bf(hnext) << 16);
        u64 pk64 = ((u64)(u32)(t + 1) << 32) | (u64)pk;
        __hip_atomic_store(hg + (((size_t)((t + 1) & 1)) << 7) + (p << 5) + (oo >> 1),
                           pk64, __ATOMIC_RELAXED, __HIP_MEMORY_SCOPE_AGENT);
      }
      out[((size_t)b * 512 + t) * 256 + o] = hn;
    }
    Yc[0] = yn0; Yc[1] = yn1; Yc[2] = yn2; Yc[3] = yn3;
    w0 = nw0; w1 = nw1; w2 = nw2; w3 = nw3;
  }
  if (s == 0) {
    cbuf[(b << 8) + o] = c;
    out[(size_t)BTH + (b << 8) + o] = hn;          // final h
    out[(size_t)BTH + 4096 + (b << 8) + o] = c;    // final c
  }
}

extern "C" void kernel_launch(void* const* d_in, const int* in_sizes, int n_in,
                              void* d_out, int out_size, void* d_ws, size_t ws_size,
                              hipStream_t stream) {
  const float* x  = (const float*)d_in[0];
  const float* Ww = (const float*)d_in[1];
  const float* Wb = (const float*)d_in[2];
  const float* Uw = (const float*)d_in[3];
  const float* Ub = (const float*)d_in[4];
  const float* Bw = (const float*)d_in[5];
  const float* Bb = (const float*)d_in[6];
  float* out = (float*)d_out;

  char* ws = (char*)d_ws;
  const size_t WX_B  = (size_t)512 * 16 * 1024 * 4;  // 33.5 MB
  const size_t XB_B  = (size_t)8192 * 256 * 2;       // 4.2 MB
  const size_t BTT_B = (size_t)65536 * 256 * 2;      // 33.5 MB
  const size_t WBT_B = (size_t)1024 * 256 * 2;       // 0.5 MB
  const size_t UBT_B = (size_t)1024 * 256 * 2;       // 0.5 MB
  const size_t CB_B  = 16384;                        // cbuf 16*256 f32
  const size_t HD_B  = 32768;                        // hdata 16*2*128 u64
  const size_t ST_B  = CB_B + HD_B;                  // 49152 = 6144 u64
  const size_t fixedB = WX_B + XB_B + BTT_B + WBT_B + UBT_B + ST_B;
  size_t avail = (ws_size > fixedB) ? (ws_size - fixedB) : 0;
  long Tc = (long)(avail / (2 * 2097152));  // two Y buffers (double-buffer)
  if (Tc > 128) Tc = 128;  // r8: 128-step chunks -> 6 launches total (was 10)
  Tc &= ~7L;
  if (Tc < 8) Tc = 8;

  size_t YB   = (size_t)Tc * 2097152;
  u16* Y0     = (u16*)ws;
  u16* Y1     = (u16*)(ws + YB);
  float* wx   = (float*)(ws + 2 * YB);
  u16* xb     = (u16*)(ws + 2 * YB + WX_B);
  u16* Btt    = (u16*)(ws + 2 * YB + WX_B + XB_B);
  u16* Wbt    = (u16*)(ws + 2 * YB + WX_B + XB_B + BTT_B);
  u16* Ubt    = (u16*)(ws + 2 * YB + WX_B + XB_B + BTT_B + WBT_B);
  char* st    = ws + 2 * YB + WX_B + XB_B + BTT_B + WBT_B + UBT_B;
  float* cbuf = (float*)st;
  u64* hdata  = (u64*)(st + CB_B);

  prep_kernel<<<14337, 256, 0, stream>>>(x, Ww, Uw, Bw, xb, Wbt, Ubt, Btt, (u64*)st);

  // fused0: wx-GEMM (256 blocks) + Y-GEMM for chunk 0 (no scan)
  {
    int Tc0 = (int)Tc;
    int ng0 = (Tc0 * 16 / 128) * 256;
    fused_kernel<<<256 + ng0, 512, 0, stream>>>(
        nullptr, wx, Ubt, Bb, cbuf, hdata, out, 0, 0,
        xb, Btt, Y0, Wbt, Wb, Ub, wx, 0, 256);
  }
  int cidx = 0;
  for (int t0 = 0; t0 < 512; t0 += (int)Tc, ++cidx) {
    int Tcur = (512 - t0 < (int)Tc) ? (512 - t0) : (int)Tc;
    int t0n = t0 + Tcur;
    u16* Ysc = (cidx & 1) ? Y1 : Y0;
    u16* Ygm = (cidx & 1) ? Y0 : Y1;
    int ng = 0;
    const u16* Ag = xb;
    if (t0n < 512) {
      int Tcn = (512 - t0n < (int)Tc) ? (512 - t0n) : (int)Tc;
      ng = (Tcn * 16 / 128) * 256;
      Ag = xb + (size_t)t0n * 4096;
    }
    fused_kernel<<<64 + ng, 512, 0, stream>>>(
        Ysc, wx, Ubt, Bb, cbuf, hdata, out, t0, Tcur,
        Ag, Btt, Ygm, Wbt, Wb, Ub, wx, 64, 0);
  }
}